// Round 12
// baseline (82.783 us; speedup 1.0000x reference)
//
#include <hip/hip_runtime.h>

#define IN_CH 256
#define OUT_CH 512
#define HW 56
#define NPIX (HW * HW)            // 3136
#define NPIX4 (NPIX / 4)          // 784
#define WROW (IN_CH * 9)          // 2304
#define NT 10
#define HB 8
#define NDOT (NT * HB)            // 80
#define SIZE_LIMIT 256
#define EPS 1e-3f

// stage1 roles (512-thread blocks): wsig (ch-pair, ALL tables) + query + zero-y + pad-x
#define WOTILE 2
#define WBLOCKS (OUT_CH / WOTILE)               // 256 — whole_w read ONCE
#define QBLOCKS IN_CH                           // 256
#define ZBLOCKS OUT_CH                          // 512
#define PBLOCKS IN_CH                           // 256
#define S1BLOCKS (WBLOCKS + QBLOCKS + ZBLOCKS + PBLOCKS)  // 1280
#define S1THR 512

// conv tiling: 4 px/thread (float4), 2 out-ch, 16 in-ch, slot-pair loop
#define COTILE 2
#define SPGRID 16
#define PT4 4                                   // ceil(784/256)
#define KSPLIT 16
#define KCH (IN_CH / KSPLIT)                    // 16

// padded x: [58 rows][64 cols] per channel
#define XPW 64
#define XPSZ (58 * XPW)                         // 3712 floats

// ws offsets (4-byte units)
#define Q_OFF       0
#define QADDR_OFF   256
#define WADDR_OFF   288
#define SLOT_OFF    (WADDR_OFF + NT * OUT_CH)
#define NACT_OFF    (SLOT_OFF + OUT_CH)
#define COMPACT_OFF (NACT_OFF + 32)
#define PART_OFF    16384                       // 16*256*3136 f ≈ 51.4 MB
#define XPAD_OFF    (PART_OFF + KSPLIT * SIZE_LIMIT * NPIX)  // + 3.8 MB

#define ROWFMA(ax, ay, az, aw, A, B, k0, k1, k2)                 \
    ax = fmaf(A.x, k0, fmaf(A.y, k1, fmaf(A.z, k2, ax)));        \
    ay = fmaf(A.y, k0, fmaf(A.z, k1, fmaf(A.w, k2, ay)));        \
    az = fmaf(A.z, k0, fmaf(A.w, k1, fmaf(B.x, k2, az)));        \
    aw = fmaf(A.w, k0, fmaf(B.x, k1, fmaf(B.y, k2, aw)));

// ---- 1. fused: weight signatures (w-stationary) + query + zero y + pad x ----
__global__ __launch_bounds__(S1THR) void k_stage1(const float* __restrict__ x,
                                                  const float* __restrict__ whole_w,
                                                  const float* __restrict__ rm_w,
                                                  float* __restrict__ wsf,
                                                  int* __restrict__ wsi,
                                                  float* __restrict__ y) {
    __shared__ float4 sW4[WOTILE][WROW / 4];  // 18.4 KB
    __shared__ int bits[NDOT][WOTILE];
    __shared__ float red[S1THR];
    int bid = blockIdx.x, tid = threadIdx.x;

    if (bid < WBLOCKS) {
        // weight-stationary: stage channel-pair weights once, stream ALL 80 rm rows
        int o0 = bid * WOTILE;
        const float4* w4 = (const float4*)(whole_w + (size_t)o0 * WROW);
        for (int i = tid; i < WOTILE * (WROW / 4); i += S1THR)
            sW4[i / (WROW / 4)][i % (WROW / 4)] = w4[i];
        __syncthreads();
        int wid = tid >> 6, lane = tid & 63;   // 8 waves x 10 dots each
        for (int k = 0; k < 10; k++) {
            int d = wid * 10 + k;
            const float4* r = (const float4*)(rm_w + (size_t)d * WROW);
            float a0 = 0.f, a1 = 0.f;
            for (int i = lane; i < WROW / 4; i += 64) {  // 9 iters
                float4 v = r[i];
                float4 w0 = sW4[0][i], w1 = sW4[1][i];
                a0 += v.x * w0.x + v.y * w0.y + v.z * w0.z + v.w * w0.w;
                a1 += v.x * w1.x + v.y * w1.y + v.z * w1.z + v.w * w1.w;
            }
            for (int m = 32; m > 0; m >>= 1) {
                a0 += __shfl_xor(a0, m, 64);
                a1 += __shfl_xor(a1, m, 64);
            }
            if (lane == 0) {
                bits[d][0] = (a0 > 0.f) ? 1 : 0;
                bits[d][1] = (a1 > 0.f) ? 1 : 0;
            }
        }
        __syncthreads();
        if (tid < NT * WOTILE) {
            int t = tid >> 1, j = tid & 1;
            int a = 0;
            #pragma unroll
            for (int h = 0; h < HB; h++) a |= bits[t * HB + h][j] << (7 - h);
            wsi[WADDR_OFF + t * OUT_CH + o0 + j] = a;
        }
    } else if (bid < WBLOCKS + QBLOCKS) {
        int c = bid - WBLOCKS;
        const float* xc = x + (size_t)c * NPIX;
        float s = 0.f;
        for (int p = tid; p < NPIX; p += S1THR) s += xc[p];
        red[tid] = s;
        __syncthreads();
        for (int off = S1THR / 2; off > 0; off >>= 1) {
            if (tid < off) red[tid] += red[tid + off];
            __syncthreads();
        }
        if (tid == 0) wsf[Q_OFF + c] = red[0] / (float)NPIX;
    } else if (bid < WBLOCKS + QBLOCKS + ZBLOCKS) {
        int o = bid - WBLOCKS - QBLOCKS;
        float4* y4 = (float4*)(y + (size_t)o * NPIX);
        float4 z4 = make_float4(0.f, 0.f, 0.f, 0.f);
        for (int i = tid; i < NPIX4; i += S1THR) y4[i] = z4;
    } else {
        int c = bid - WBLOCKS - QBLOCKS - ZBLOCKS;
        const float* xc = x + (size_t)c * NPIX;
        float* xp = wsf + XPAD_OFF + (size_t)c * XPSZ;
        for (int i = tid; i < XPSZ; i += S1THR) {
            int rr = i >> 6, cc = i & 63;
            int sr = rr - 1, sc = cc - 1;
            float v = (sr >= 0 && sr < HW && sc >= 0 && sc < HW) ? xc[sr * HW + sc] : 0.f;
            xp[i] = v;
        }
    }
}

// ---- 2. fused: query signatures + histogram + top-k + compaction (512 thr) ----
__global__ void k_select(const float* __restrict__ rm_q, const float* __restrict__ wsf,
                         int* __restrict__ wsi) {
    int tid = threadIdx.x; // 512
    __shared__ float qs[IN_CH];
    __shared__ int qbits[NDOT];
    __shared__ int qsig[NT];
    __shared__ int hist[OUT_CH];
    __shared__ int sel[OUT_CH];
    if (tid < IN_CH) qs[tid] = wsf[Q_OFF + tid];
    __syncthreads();
    if (tid < NDOT * 4) {
        int d = tid >> 2, part = tid & 3;
        const float* r = rm_q + d * IN_CH + part * 64;
        const float* qq = qs + part * 64;
        float acc = 0.f;
        for (int k = 0; k < 64; k++) acc = fmaf(r[k], qq[k], acc);
        acc += __shfl_xor(acc, 1, 64);
        acc += __shfl_xor(acc, 2, 64);
        if (part == 0) qbits[d] = (acc > 0.f) ? 1 : 0;
    }
    __syncthreads();
    if (tid < NT) {
        int a = 0;
        #pragma unroll
        for (int h = 0; h < HB; h++) a |= qbits[tid * HB + h] << (7 - h);
        qsig[tid] = a;
        wsi[QADDR_OFF + tid] = a;
    }
    __syncthreads();
    int h = 0;
    for (int t = 0; t < NT; t++) h += (wsi[WADDR_OFF + t * OUT_CH + tid] == qsig[t]) ? 1 : 0;
    hist[tid] = h;
    __syncthreads();
    int rank = 0;
    for (int j = 0; j < OUT_CH; j++) {
        int hj = hist[j];
        rank += (hj > h || (hj == h && j < tid)) ? 1 : 0;
    }
    int s = (h > 0 && rank < SIZE_LIMIT) ? 1 : 0;
    sel[tid] = s;
    wsi[SLOT_OFF + tid] = 0;
    __syncthreads();
    if (s) {
        int pos = 0;
        for (int j = 0; j < tid; j++) pos += sel[j];
        wsi[COMPACT_OFF + pos] = tid;
        wsi[SLOT_OFF + tid] = pos + 1;
    }
    if (tid == 0) {
        int c = 0;
        for (int j = 0; j < OUT_CH; j++) c += sel[j];
        wsi[NACT_OFF] = c;
    }
}

// ---- 3. sparse conv on padded x: named scalars only ----
__global__ __launch_bounds__(256) void k_conv(const float* __restrict__ whole_w,
                                              const int* __restrict__ wsi,
                                              float* __restrict__ wsf) {
    int nact = wsi[NACT_OFF];
    int tid = threadIdx.x;
    int z = blockIdx.z;
    int i4 = blockIdx.x * 256 + tid;
    bool pv = i4 < NPIX4;
    int i4c = pv ? i4 : 0;
    int r = i4c / 14, g4 = i4c - r * 14;
    const float* xpb = wsf + XPAD_OFF + (size_t)z * KCH * XPSZ + r * XPW + 4 * g4;

    for (int sp = blockIdx.y; sp * COTILE < nact; sp += SPGRID) {
        int slot0 = sp * COTILE;
        bool s1v = (slot0 + 1) < nact;
        int o0 = wsi[COMPACT_OFF + slot0];
        int o1 = s1v ? wsi[COMPACT_OFF + slot0 + 1] : o0;
        int ou0 = __builtin_amdgcn_readfirstlane(o0);
        int ou1 = __builtin_amdgcn_readfirstlane(o1);
        const float* wp0 = whole_w + (size_t)ou0 * WROW + z * (KCH * 9);
        const float* wp1 = whole_w + (size_t)ou1 * WROW + z * (KCH * 9);

        float a0x = 0.f, a0y = 0.f, a0z = 0.f, a0w = 0.f;
        float a1x = 0.f, a1y = 0.f, a1z = 0.f, a1w = 0.f;
        for (int c = 0; c < KCH; ++c) {
            const float* xc = xpb + (size_t)c * XPSZ;
            float4 t0a = *(const float4*)(xc);
            float4 t0b = *(const float4*)(xc + 4);
            float4 t1a = *(const float4*)(xc + XPW);
            float4 t1b = *(const float4*)(xc + XPW + 4);
            float4 t2a = *(const float4*)(xc + 2 * XPW);
            float4 t2b = *(const float4*)(xc + 2 * XPW + 4);
            const float* w0 = wp0 + c * 9;
            const float* w1 = wp1 + c * 9;
            ROWFMA(a0x, a0y, a0z, a0w, t0a, t0b, w0[0], w0[1], w0[2])
            ROWFMA(a0x, a0y, a0z, a0w, t1a, t1b, w0[3], w0[4], w0[5])
            ROWFMA(a0x, a0y, a0z, a0w, t2a, t2b, w0[6], w0[7], w0[8])
            ROWFMA(a1x, a1y, a1z, a1w, t0a, t0b, w1[0], w1[1], w1[2])
            ROWFMA(a1x, a1y, a1z, a1w, t1a, t1b, w1[3], w1[4], w1[5])
            ROWFMA(a1x, a1y, a1z, a1w, t2a, t2b, w1[6], w1[7], w1[8])
        }
        if (pv) {
            float* pb = wsf + PART_OFF + ((size_t)z * SIZE_LIMIT + slot0) * NPIX + 4 * (size_t)i4;
            *(float4*)pb = make_float4(a0x, a0y, a0z, a0w);
            if (s1v) *(float4*)(pb + NPIX) = make_float4(a1x, a1y, a1z, a1w);
        }
    }
}

// ---- 4. combine 16 slabs + BN (batch stats) + ReLU, 1024 threads ----
__global__ __launch_bounds__(1024) void k_fin(const int* __restrict__ wsi,
                                              const float* __restrict__ wsf,
                                              const float* __restrict__ gamma,
                                              const float* __restrict__ beta,
                                              float* __restrict__ y) {
    int s = blockIdx.x, tid = threadIdx.x;
    if (s >= wsi[NACT_OFF]) return;
    int o = wsi[COMPACT_OFF + s];
    const float* base0 = wsf + PART_OFF + (size_t)s * NPIX;
    float4 v = make_float4(0.f, 0.f, 0.f, 0.f);
    if (tid < NPIX4) {
        const float* bp = base0 + 4 * (size_t)tid;
        #pragma unroll
        for (int zz = 0; zz < KSPLIT; zz++) {
            float4 t = *(const float4*)(bp + (size_t)zz * SIZE_LIMIT * NPIX);
            v.x += t.x; v.y += t.y; v.z += t.z; v.w += t.w;
        }
    }
    float sum = v.x + v.y + v.z + v.w;
    float sq = v.x * v.x + v.y * v.y + v.z * v.z + v.w * v.w;
    __shared__ float rs[1024], rq[1024];
    __shared__ float mv[2];
    rs[tid] = sum; rq[tid] = sq;
    __syncthreads();
    for (int off = 512; off > 0; off >>= 1) {
        if (tid < off) { rs[tid] += rs[tid + off]; rq[tid] += rq[tid + off]; }
        __syncthreads();
    }
    if (tid == 0) {
        float mean = rs[0] / (float)NPIX;
        float var = rq[0] / (float)NPIX - mean * mean;
        float inv = 1.0f / sqrtf(var + EPS);
        float sc = inv * gamma[o];
        mv[0] = sc;
        mv[1] = beta[o] - mean * sc;
    }
    __syncthreads();
    if (tid < NPIX4) {
        float scale = mv[0], shift = mv[1];
        float4 a = v;
        a.x = fmaf(a.x, scale, shift); a.x = (a.x > 0.f) ? a.x : 0.f;
        a.y = fmaf(a.y, scale, shift); a.y = (a.y > 0.f) ? a.y : 0.f;
        a.z = fmaf(a.z, scale, shift); a.z = (a.z > 0.f) ? a.z : 0.f;
        a.w = fmaf(a.w, scale, shift); a.w = (a.w > 0.f) ? a.w : 0.f;
        ((float4*)(y + (size_t)o * NPIX))[tid] = a;
    }
}

extern "C" void kernel_launch(void* const* d_in, const int* in_sizes, int n_in,
                              void* d_out, int out_size, void* d_ws, size_t ws_size,
                              hipStream_t stream) {
    const float* x       = (const float*)d_in[0];
    const float* whole_w = (const float*)d_in[1];
    const float* rm_w    = (const float*)d_in[2];
    const float* rm_q    = (const float*)d_in[3];
    const float* gamma   = (const float*)d_in[4];
    const float* beta    = (const float*)d_in[5];
    float* out = (float*)d_out;
    float* wsf = (float*)d_ws;
    int*   wsi = (int*)d_ws;

    k_stage1<<<S1BLOCKS, S1THR, 0, stream>>>(x, whole_w, rm_w, wsf, wsi, out);
    k_select<<<1, OUT_CH, 0, stream>>>(rm_q, wsf, wsi);
    k_conv<<<dim3(PT4, SPGRID, KSPLIT), 256, 0, stream>>>(whole_w, wsi, wsf);
    k_fin<<<SIZE_LIMIT, 1024, 0, stream>>>(wsi, wsf, gamma, beta, out);
}

// Round 13
// 73.348 us; speedup vs baseline: 1.1286x; 1.1286x over previous
//
#include <hip/hip_runtime.h>

#define IN_CH 256
#define OUT_CH 512
#define HW 56
#define NPIX (HW * HW)            // 3136
#define NPIX4 (NPIX / 4)          // 784
#define WROW (IN_CH * 9)          // 2304
#define NT 10
#define HB 8
#define NDOT (NT * HB)            // 80
#define SIZE_LIMIT 256
#define EPS 1e-3f

// aux roles
#define QBLOCKS IN_CH                           // 256
#define ZBLOCKS OUT_CH                          // 512
#define PBLOCKS IN_CH                           // 256
#define AUXBLOCKS (QBLOCKS + ZBLOCKS + PBLOCKS) // 1024

// conv tiling: 4 px/thread (float4), 2 out-ch, 16 in-ch, slot-pair loop
#define COTILE 2
#define SPGRID 16
#define PT4 4                                   // ceil(784/256)
#define KSPLIT 16
#define KCH (IN_CH / KSPLIT)                    // 16

// padded x: [58 rows][64 cols] per channel
#define XPW 64
#define XPSZ (58 * XPW)                         // 3712 floats

// ws offsets (4-byte units)
#define Q_OFF       0
#define QADDR_OFF   256
#define WADDR_OFF   288
#define SLOT_OFF    (WADDR_OFF + NT * OUT_CH)
#define NACT_OFF    (SLOT_OFF + OUT_CH)
#define COMPACT_OFF (NACT_OFF + 32)
#define PART_OFF    16384                       // 16*256*3136 f ≈ 51.4 MB
#define XPAD_OFF    (PART_OFF + KSPLIT * SIZE_LIMIT * NPIX)  // + 3.8 MB

#define ROWFMA(ax, ay, az, aw, A, B, k0, k1, k2)                 \
    ax = fmaf(A.x, k0, fmaf(A.y, k1, fmaf(A.z, k2, ax)));        \
    ay = fmaf(A.y, k0, fmaf(A.z, k1, fmaf(A.w, k2, ay)));        \
    az = fmaf(A.z, k0, fmaf(A.w, k1, fmaf(B.x, k2, az)));        \
    aw = fmaf(A.w, k0, fmaf(B.x, k1, fmaf(B.y, k2, aw)));

// ---- 1a. aux: global-avg-pool query + zero y + pad x ----
__global__ __launch_bounds__(256) void k_aux(const float* __restrict__ x,
                                             float* __restrict__ wsf,
                                             float* __restrict__ y) {
    __shared__ float red[256];
    int bid = blockIdx.x, tid = threadIdx.x;
    if (bid < QBLOCKS) {
        int c = bid;
        const float* xc = x + (size_t)c * NPIX;
        float s = 0.f;
        for (int p = tid; p < NPIX; p += 256) s += xc[p];
        red[tid] = s;
        __syncthreads();
        for (int off = 128; off > 0; off >>= 1) {
            if (tid < off) red[tid] += red[tid + off];
            __syncthreads();
        }
        if (tid == 0) wsf[Q_OFF + c] = red[0] / (float)NPIX;
    } else if (bid < QBLOCKS + ZBLOCKS) {
        int o = bid - QBLOCKS;
        float4* y4 = (float4*)(y + (size_t)o * NPIX);
        float4 z4 = make_float4(0.f, 0.f, 0.f, 0.f);
        for (int i = tid; i < NPIX4; i += 256) y4[i] = z4;
    } else {
        int c = bid - QBLOCKS - ZBLOCKS;
        const float* xc = x + (size_t)c * NPIX;
        float* xp = wsf + XPAD_OFF + (size_t)c * XPSZ;
        for (int i = tid; i < XPSZ; i += 256) {
            int rr = i >> 6, cc = i & 63;
            int sr = rr - 1, sc = cc - 1;
            float v = (sr >= 0 && sr < HW && sc >= 0 && sc < HW) ? xc[sr * HW + sc] : 0.f;
            xp[i] = v;
        }
    }
}

// ---- 1b. weight signatures: (ch-pair, table) blocks, 2-dot x 2-ch register tile ----
__global__ __launch_bounds__(256) void k_wsig(const float* __restrict__ whole_w,
                                              const float* __restrict__ rm_w,
                                              int* __restrict__ wsi) {
    __shared__ float4 sW4[2][WROW / 4];   // 18.4 KB
    __shared__ int bits[HB][2];
    int o0 = blockIdx.x * 2, dg = blockIdx.y;
    int tid = threadIdx.x;
    const float4* w4 = (const float4*)(whole_w + (size_t)o0 * WROW);
    for (int i = tid; i < 2 * (WROW / 4); i += 256)
        sW4[i / (WROW / 4)][i % (WROW / 4)] = w4[i];
    __syncthreads();
    int wid = tid >> 6, lane = tid & 63;
    int d0 = dg * HB + wid * 2;   // 4 waves x 2 dots = all 8 bits of table dg
    const float4* r0 = (const float4*)(rm_w + (size_t)d0 * WROW);
    const float4* r1 = (const float4*)(rm_w + (size_t)(d0 + 1) * WROW);
    float a00 = 0.f, a01 = 0.f, a10 = 0.f, a11 = 0.f;
    for (int i = lane; i < WROW / 4; i += 64) {  // 9 iters, 2 indep global loads each
        float4 v0 = r0[i], v1 = r1[i];
        float4 w0 = sW4[0][i], w1 = sW4[1][i];
        a00 += v0.x * w0.x + v0.y * w0.y + v0.z * w0.z + v0.w * w0.w;
        a01 += v0.x * w1.x + v0.y * w1.y + v0.z * w1.z + v0.w * w1.w;
        a10 += v1.x * w0.x + v1.y * w0.y + v1.z * w0.z + v1.w * w0.w;
        a11 += v1.x * w1.x + v1.y * w1.y + v1.z * w1.z + v1.w * w1.w;
    }
    for (int m = 32; m > 0; m >>= 1) {
        a00 += __shfl_xor(a00, m, 64);
        a01 += __shfl_xor(a01, m, 64);
        a10 += __shfl_xor(a10, m, 64);
        a11 += __shfl_xor(a11, m, 64);
    }
    if (lane == 0) {
        bits[wid * 2][0]     = (a00 > 0.f) ? 1 : 0;
        bits[wid * 2][1]     = (a01 > 0.f) ? 1 : 0;
        bits[wid * 2 + 1][0] = (a10 > 0.f) ? 1 : 0;
        bits[wid * 2 + 1][1] = (a11 > 0.f) ? 1 : 0;
    }
    __syncthreads();
    if (tid < 2) {
        int a = 0;
        #pragma unroll
        for (int h = 0; h < HB; h++) a |= bits[h][tid] << (7 - h);
        wsi[WADDR_OFF + dg * OUT_CH + o0 + tid] = a;
    }
}

// ---- 2. fused: query signatures + histogram + top-k + compaction (512 thr) ----
__global__ void k_select(const float* __restrict__ rm_q, const float* __restrict__ wsf,
                         int* __restrict__ wsi) {
    int tid = threadIdx.x; // 512
    __shared__ float qs[IN_CH];
    __shared__ int qbits[NDOT];
    __shared__ int qsig[NT];
    __shared__ int hist[OUT_CH];
    __shared__ int sel[OUT_CH];
    if (tid < IN_CH) qs[tid] = wsf[Q_OFF + tid];
    __syncthreads();
    if (tid < NDOT * 4) {
        int d = tid >> 2, part = tid & 3;
        const float* r = rm_q + d * IN_CH + part * 64;
        const float* qq = qs + part * 64;
        float acc = 0.f;
        for (int k = 0; k < 64; k++) acc = fmaf(r[k], qq[k], acc);
        acc += __shfl_xor(acc, 1, 64);
        acc += __shfl_xor(acc, 2, 64);
        if (part == 0) qbits[d] = (acc > 0.f) ? 1 : 0;
    }
    __syncthreads();
    if (tid < NT) {
        int a = 0;
        #pragma unroll
        for (int h = 0; h < HB; h++) a |= qbits[tid * HB + h] << (7 - h);
        qsig[tid] = a;
        wsi[QADDR_OFF + tid] = a;
    }
    __syncthreads();
    int h = 0;
    for (int t = 0; t < NT; t++) h += (wsi[WADDR_OFF + t * OUT_CH + tid] == qsig[t]) ? 1 : 0;
    hist[tid] = h;
    __syncthreads();
    int rank = 0;
    for (int j = 0; j < OUT_CH; j++) {
        int hj = hist[j];
        rank += (hj > h || (hj == h && j < tid)) ? 1 : 0;
    }
    int s = (h > 0 && rank < SIZE_LIMIT) ? 1 : 0;
    sel[tid] = s;
    wsi[SLOT_OFF + tid] = 0;
    __syncthreads();
    if (s) {
        int pos = 0;
        for (int j = 0; j < tid; j++) pos += sel[j];
        wsi[COMPACT_OFF + pos] = tid;
        wsi[SLOT_OFF + tid] = pos + 1;
    }
    if (tid == 0) {
        int c = 0;
        for (int j = 0; j < OUT_CH; j++) c += sel[j];
        wsi[NACT_OFF] = c;
    }
}

// ---- 3. sparse conv on padded x: named scalars only ----
__global__ __launch_bounds__(256) void k_conv(const float* __restrict__ whole_w,
                                              const int* __restrict__ wsi,
                                              float* __restrict__ wsf) {
    int nact = wsi[NACT_OFF];
    int tid = threadIdx.x;
    int z = blockIdx.z;
    int i4 = blockIdx.x * 256 + tid;
    bool pv = i4 < NPIX4;
    int i4c = pv ? i4 : 0;
    int r = i4c / 14, g4 = i4c - r * 14;
    const float* xpb = wsf + XPAD_OFF + (size_t)z * KCH * XPSZ + r * XPW + 4 * g4;

    for (int sp = blockIdx.y; sp * COTILE < nact; sp += SPGRID) {
        int slot0 = sp * COTILE;
        bool s1v = (slot0 + 1) < nact;
        int o0 = wsi[COMPACT_OFF + slot0];
        int o1 = s1v ? wsi[COMPACT_OFF + slot0 + 1] : o0;
        int ou0 = __builtin_amdgcn_readfirstlane(o0);
        int ou1 = __builtin_amdgcn_readfirstlane(o1);
        const float* wp0 = whole_w + (size_t)ou0 * WROW + z * (KCH * 9);
        const float* wp1 = whole_w + (size_t)ou1 * WROW + z * (KCH * 9);

        float a0x = 0.f, a0y = 0.f, a0z = 0.f, a0w = 0.f;
        float a1x = 0.f, a1y = 0.f, a1z = 0.f, a1w = 0.f;
        for (int c = 0; c < KCH; ++c) {
            const float* xc = xpb + (size_t)c * XPSZ;
            float4 t0a = *(const float4*)(xc);
            float4 t0b = *(const float4*)(xc + 4);
            float4 t1a = *(const float4*)(xc + XPW);
            float4 t1b = *(const float4*)(xc + XPW + 4);
            float4 t2a = *(const float4*)(xc + 2 * XPW);
            float4 t2b = *(const float4*)(xc + 2 * XPW + 4);
            const float* w0 = wp0 + c * 9;
            const float* w1 = wp1 + c * 9;
            ROWFMA(a0x, a0y, a0z, a0w, t0a, t0b, w0[0], w0[1], w0[2])
            ROWFMA(a0x, a0y, a0z, a0w, t1a, t1b, w0[3], w0[4], w0[5])
            ROWFMA(a0x, a0y, a0z, a0w, t2a, t2b, w0[6], w0[7], w0[8])
            ROWFMA(a1x, a1y, a1z, a1w, t0a, t0b, w1[0], w1[1], w1[2])
            ROWFMA(a1x, a1y, a1z, a1w, t1a, t1b, w1[3], w1[4], w1[5])
            ROWFMA(a1x, a1y, a1z, a1w, t2a, t2b, w1[6], w1[7], w1[8])
        }
        if (pv) {
            float* pb = wsf + PART_OFF + ((size_t)z * SIZE_LIMIT + slot0) * NPIX + 4 * (size_t)i4;
            *(float4*)pb = make_float4(a0x, a0y, a0z, a0w);
            if (s1v) *(float4*)(pb + NPIX) = make_float4(a1x, a1y, a1z, a1w);
        }
    }
}

// ---- 4. combine 16 slabs + BN (batch stats) + ReLU, 1024 threads ----
__global__ __launch_bounds__(1024) void k_fin(const int* __restrict__ wsi,
                                              const float* __restrict__ wsf,
                                              const float* __restrict__ gamma,
                                              const float* __restrict__ beta,
                                              float* __restrict__ y) {
    int s = blockIdx.x, tid = threadIdx.x;
    if (s >= wsi[NACT_OFF]) return;
    int o = wsi[COMPACT_OFF + s];
    const float* base0 = wsf + PART_OFF + (size_t)s * NPIX;
    float4 v = make_float4(0.f, 0.f, 0.f, 0.f);
    if (tid < NPIX4) {
        const float* bp = base0 + 4 * (size_t)tid;
        #pragma unroll
        for (int zz = 0; zz < KSPLIT; zz++) {
            float4 t = *(const float4*)(bp + (size_t)zz * SIZE_LIMIT * NPIX);
            v.x += t.x; v.y += t.y; v.z += t.z; v.w += t.w;
        }
    }
    float sum = v.x + v.y + v.z + v.w;
    float sq = v.x * v.x + v.y * v.y + v.z * v.z + v.w * v.w;
    __shared__ float rs[1024], rq[1024];
    __shared__ float mv[2];
    rs[tid] = sum; rq[tid] = sq;
    __syncthreads();
    for (int off = 512; off > 0; off >>= 1) {
        if (tid < off) { rs[tid] += rs[tid + off]; rq[tid] += rq[tid + off]; }
        __syncthreads();
    }
    if (tid == 0) {
        float mean = rs[0] / (float)NPIX;
        float var = rq[0] / (float)NPIX - mean * mean;
        float inv = 1.0f / sqrtf(var + EPS);
        float sc = inv * gamma[o];
        mv[0] = sc;
        mv[1] = beta[o] - mean * sc;
    }
    __syncthreads();
    if (tid < NPIX4) {
        float scale = mv[0], shift = mv[1];
        float4 a = v;
        a.x = fmaf(a.x, scale, shift); a.x = (a.x > 0.f) ? a.x : 0.f;
        a.y = fmaf(a.y, scale, shift); a.y = (a.y > 0.f) ? a.y : 0.f;
        a.z = fmaf(a.z, scale, shift); a.z = (a.z > 0.f) ? a.z : 0.f;
        a.w = fmaf(a.w, scale, shift); a.w = (a.w > 0.f) ? a.w : 0.f;
        ((float4*)(y + (size_t)o * NPIX))[tid] = a;
    }
}

extern "C" void kernel_launch(void* const* d_in, const int* in_sizes, int n_in,
                              void* d_out, int out_size, void* d_ws, size_t ws_size,
                              hipStream_t stream) {
    const float* x       = (const float*)d_in[0];
    const float* whole_w = (const float*)d_in[1];
    const float* rm_w    = (const float*)d_in[2];
    const float* rm_q    = (const float*)d_in[3];
    const float* gamma   = (const float*)d_in[4];
    const float* beta    = (const float*)d_in[5];
    float* out = (float*)d_out;
    float* wsf = (float*)d_ws;
    int*   wsi = (int*)d_ws;

    k_wsig<<<dim3(OUT_CH / 2, NT), 256, 0, stream>>>(whole_w, rm_w, wsi);
    k_aux<<<AUXBLOCKS, 256, 0, stream>>>(x, wsf, out);
    k_select<<<1, OUT_CH, 0, stream>>>(rm_q, wsf, wsi);
    k_conv<<<dim3(PT4, SPGRID, KSPLIT), 256, 0, stream>>>(whole_w, wsi, wsf);
    k_fin<<<SIZE_LIMIT, 1024, 0, stream>>>(wsi, wsf, gamma, beta, out);
}

// Round 14
// 60.801 us; speedup vs baseline: 1.3616x; 1.2064x over previous
//
#include <hip/hip_runtime.h>

#define IN_CH 256
#define OUT_CH 512
#define HW 56
#define NPIX (HW * HW)            // 3136
#define NPIX4 (NPIX / 4)          // 784
#define WROW (IN_CH * 9)          // 2304
#define NT 10
#define HB 8
#define NDOT (NT * HB)            // 80
#define SIZE_LIMIT 256
#define EPS 1e-3f

// stage1 roles: wsig (ch-pair x table) + query + zero-y + pad-x
#define WOTILE 2
#define WSBLOCKS ((OUT_CH / WOTILE) * NT)       // 2560
#define QBLOCKS IN_CH                           // 256
#define ZBLOCKS OUT_CH                          // 512
#define PBLOCKS IN_CH                           // 256
#define S1BLOCKS (WSBLOCKS + QBLOCKS + ZBLOCKS + PBLOCKS)  // 3584

// conv tiling: 4 px/thread (float4), 4 out-ch, 16 in-ch, slot-quad loop
#define COTILE 4
#define SPGRID 8
#define PT4 4                                   // ceil(784/256)
#define KSPLIT 16
#define KCH (IN_CH / KSPLIT)                    // 16

// padded x: [58 rows][64 cols] per channel
#define XPW 64
#define XPSZ (58 * XPW)                         // 3712 floats

// ws offsets (4-byte units)
#define Q_OFF       0
#define QADDR_OFF   256
#define WADDR_OFF   288
#define SLOT_OFF    (WADDR_OFF + NT * OUT_CH)
#define NACT_OFF    (SLOT_OFF + OUT_CH)
#define COMPACT_OFF (NACT_OFF + 32)
#define PART_OFF    16384                       // 16*256*3136 f ≈ 51.4 MB
#define XPAD_OFF    (PART_OFF + KSPLIT * SIZE_LIMIT * NPIX)  // + 3.8 MB

#define ROWFMA(ax, ay, az, aw, A, B, k0, k1, k2)                 \
    ax = fmaf(A.x, k0, fmaf(A.y, k1, fmaf(A.z, k2, ax)));        \
    ay = fmaf(A.y, k0, fmaf(A.z, k1, fmaf(A.w, k2, ay)));        \
    az = fmaf(A.z, k0, fmaf(A.w, k1, fmaf(B.x, k2, az)));        \
    aw = fmaf(A.w, k0, fmaf(B.x, k1, fmaf(B.y, k2, aw)));

// ---- 1. fused: weight signatures + query avg-pool + zero y + pad x ----
__global__ __launch_bounds__(256) void k_stage1(const float* __restrict__ x,
                                                const float* __restrict__ whole_w,
                                                const float* __restrict__ rm_w,
                                                float* __restrict__ wsf,
                                                int* __restrict__ wsi,
                                                float* __restrict__ y) {
    __shared__ float4 sW4[WOTILE][WROW / 4];   // 18.4 KB
    __shared__ int bits[HB][WOTILE];
    __shared__ float red[256];
    int bid = blockIdx.x, tid = threadIdx.x;

    if (bid < WSBLOCKS) {
        // wsig role: channel-pair o0,o0+1 x table dg (2-dot x 2-ch register tile)
        int opair = bid / NT, dg = bid - opair * NT;
        int o0 = opair * WOTILE;
        const float4* w4 = (const float4*)(whole_w + (size_t)o0 * WROW);
        for (int i = tid; i < WOTILE * (WROW / 4); i += 256)
            sW4[i / (WROW / 4)][i % (WROW / 4)] = w4[i];
        __syncthreads();
        int wid = tid >> 6, lane = tid & 63;
        int d0 = dg * HB + wid * 2;   // 4 waves x 2 dots = all 8 bits of table dg
        const float4* r0 = (const float4*)(rm_w + (size_t)d0 * WROW);
        const float4* r1 = (const float4*)(rm_w + (size_t)(d0 + 1) * WROW);
        float a00 = 0.f, a01 = 0.f, a10 = 0.f, a11 = 0.f;
        for (int i = lane; i < WROW / 4; i += 64) {  // 9 iters
            float4 v0 = r0[i], v1 = r1[i];
            float4 w0 = sW4[0][i], w1 = sW4[1][i];
            a00 += v0.x * w0.x + v0.y * w0.y + v0.z * w0.z + v0.w * w0.w;
            a01 += v0.x * w1.x + v0.y * w1.y + v0.z * w1.z + v0.w * w1.w;
            a10 += v1.x * w0.x + v1.y * w0.y + v1.z * w0.z + v1.w * w0.w;
            a11 += v1.x * w1.x + v1.y * w1.y + v1.z * w1.z + v1.w * w1.w;
        }
        for (int m = 32; m > 0; m >>= 1) {
            a00 += __shfl_xor(a00, m, 64);
            a01 += __shfl_xor(a01, m, 64);
            a10 += __shfl_xor(a10, m, 64);
            a11 += __shfl_xor(a11, m, 64);
        }
        if (lane == 0) {
            bits[wid * 2][0]     = (a00 > 0.f) ? 1 : 0;
            bits[wid * 2][1]     = (a01 > 0.f) ? 1 : 0;
            bits[wid * 2 + 1][0] = (a10 > 0.f) ? 1 : 0;
            bits[wid * 2 + 1][1] = (a11 > 0.f) ? 1 : 0;
        }
        __syncthreads();
        if (tid < WOTILE) {
            int a = 0;
            #pragma unroll
            for (int h = 0; h < HB; h++) a |= bits[h][tid] << (7 - h);
            wsi[WADDR_OFF + dg * OUT_CH + o0 + tid] = a;
        }
    } else if (bid < WSBLOCKS + QBLOCKS) {
        int c = bid - WSBLOCKS;
        const float* xc = x + (size_t)c * NPIX;
        float s = 0.f;
        for (int p = tid; p < NPIX; p += 256) s += xc[p];
        red[tid] = s;
        __syncthreads();
        for (int off = 128; off > 0; off >>= 1) {
            if (tid < off) red[tid] += red[tid + off];
            __syncthreads();
        }
        if (tid == 0) wsf[Q_OFF + c] = red[0] / (float)NPIX;
    } else if (bid < WSBLOCKS + QBLOCKS + ZBLOCKS) {
        int o = bid - WSBLOCKS - QBLOCKS;
        float4* y4 = (float4*)(y + (size_t)o * NPIX);
        float4 z4 = make_float4(0.f, 0.f, 0.f, 0.f);
        for (int i = tid; i < NPIX4; i += 256) y4[i] = z4;
    } else {
        int c = bid - WSBLOCKS - QBLOCKS - ZBLOCKS;
        const float* xc = x + (size_t)c * NPIX;
        float* xp = wsf + XPAD_OFF + (size_t)c * XPSZ;
        for (int i = tid; i < XPSZ; i += 256) {
            int rr = i >> 6, cc = i & 63;
            int sr = rr - 1, sc = cc - 1;
            float v = (sr >= 0 && sr < HW && sc >= 0 && sc < HW) ? xc[sr * HW + sc] : 0.f;
            xp[i] = v;
        }
    }
}

// ---- 2. fused: query signatures + histogram + top-k + compaction (512 thr) ----
__global__ void k_select(const float* __restrict__ rm_q, const float* __restrict__ wsf,
                         int* __restrict__ wsi) {
    int tid = threadIdx.x; // 512
    __shared__ float qs[IN_CH];
    __shared__ int qbits[NDOT];
    __shared__ int qsig[NT];
    __shared__ int hist[OUT_CH];
    __shared__ int sel[OUT_CH];
    if (tid < IN_CH) qs[tid] = wsf[Q_OFF + tid];
    __syncthreads();
    if (tid < NDOT * 4) {
        int d = tid >> 2, part = tid & 3;
        const float* r = rm_q + d * IN_CH + part * 64;
        const float* qq = qs + part * 64;
        float acc = 0.f;
        for (int k = 0; k < 64; k++) acc = fmaf(r[k], qq[k], acc);
        acc += __shfl_xor(acc, 1, 64);
        acc += __shfl_xor(acc, 2, 64);
        if (part == 0) qbits[d] = (acc > 0.f) ? 1 : 0;
    }
    __syncthreads();
    if (tid < NT) {
        int a = 0;
        #pragma unroll
        for (int h = 0; h < HB; h++) a |= qbits[tid * HB + h] << (7 - h);
        qsig[tid] = a;
        wsi[QADDR_OFF + tid] = a;
    }
    __syncthreads();
    int h = 0;
    for (int t = 0; t < NT; t++) h += (wsi[WADDR_OFF + t * OUT_CH + tid] == qsig[t]) ? 1 : 0;
    hist[tid] = h;
    __syncthreads();
    int rank = 0;
    for (int j = 0; j < OUT_CH; j++) {
        int hj = hist[j];
        rank += (hj > h || (hj == h && j < tid)) ? 1 : 0;
    }
    int s = (h > 0 && rank < SIZE_LIMIT) ? 1 : 0;
    sel[tid] = s;
    wsi[SLOT_OFF + tid] = 0;
    __syncthreads();
    if (s) {
        int pos = 0;
        for (int j = 0; j < tid; j++) pos += sel[j];
        wsi[COMPACT_OFF + pos] = tid;
        wsi[SLOT_OFF + tid] = pos + 1;
    }
    if (tid == 0) {
        int c = 0;
        for (int j = 0; j < OUT_CH; j++) c += sel[j];
        wsi[NACT_OFF] = c;
    }
}

// ---- 3. sparse conv on padded x: 4 out-ch, named scalars only ----
__global__ __launch_bounds__(256) void k_conv(const float* __restrict__ whole_w,
                                              const int* __restrict__ wsi,
                                              float* __restrict__ wsf) {
    int nact = wsi[NACT_OFF];
    int tid = threadIdx.x;
    int z = blockIdx.z;
    int i4 = blockIdx.x * 256 + tid;
    bool pv = i4 < NPIX4;
    int i4c = pv ? i4 : 0;
    int r = i4c / 14, g4 = i4c - r * 14;
    const float* xpb = wsf + XPAD_OFF + (size_t)z * KCH * XPSZ + r * XPW + 4 * g4;

    for (int sp = blockIdx.y; sp * COTILE < nact; sp += SPGRID) {
        int slot0 = sp * COTILE;
        bool v1 = (slot0 + 1) < nact, v2 = (slot0 + 2) < nact, v3 = (slot0 + 3) < nact;
        int o0 = wsi[COMPACT_OFF + slot0];
        int o1 = v1 ? wsi[COMPACT_OFF + slot0 + 1] : o0;
        int o2 = v2 ? wsi[COMPACT_OFF + slot0 + 2] : o0;
        int o3 = v3 ? wsi[COMPACT_OFF + slot0 + 3] : o0;
        const float* wp0 = whole_w + (size_t)__builtin_amdgcn_readfirstlane(o0) * WROW + z * (KCH * 9);
        const float* wp1 = whole_w + (size_t)__builtin_amdgcn_readfirstlane(o1) * WROW + z * (KCH * 9);
        const float* wp2 = whole_w + (size_t)__builtin_amdgcn_readfirstlane(o2) * WROW + z * (KCH * 9);
        const float* wp3 = whole_w + (size_t)__builtin_amdgcn_readfirstlane(o3) * WROW + z * (KCH * 9);

        float a0x = 0.f, a0y = 0.f, a0z = 0.f, a0w = 0.f;
        float a1x = 0.f, a1y = 0.f, a1z = 0.f, a1w = 0.f;
        float a2x = 0.f, a2y = 0.f, a2z = 0.f, a2w = 0.f;
        float a3x = 0.f, a3y = 0.f, a3z = 0.f, a3w = 0.f;
        for (int c = 0; c < KCH; ++c) {
            const float* xc = xpb + (size_t)c * XPSZ;
            float4 t0a = *(const float4*)(xc);
            float4 t0b = *(const float4*)(xc + 4);
            float4 t1a = *(const float4*)(xc + XPW);
            float4 t1b = *(const float4*)(xc + XPW + 4);
            float4 t2a = *(const float4*)(xc + 2 * XPW);
            float4 t2b = *(const float4*)(xc + 2 * XPW + 4);
            const float* w0 = wp0 + c * 9;
            const float* w1 = wp1 + c * 9;
            const float* w2 = wp2 + c * 9;
            const float* w3 = wp3 + c * 9;
            ROWFMA(a0x, a0y, a0z, a0w, t0a, t0b, w0[0], w0[1], w0[2])
            ROWFMA(a0x, a0y, a0z, a0w, t1a, t1b, w0[3], w0[4], w0[5])
            ROWFMA(a0x, a0y, a0z, a0w, t2a, t2b, w0[6], w0[7], w0[8])
            ROWFMA(a1x, a1y, a1z, a1w, t0a, t0b, w1[0], w1[1], w1[2])
            ROWFMA(a1x, a1y, a1z, a1w, t1a, t1b, w1[3], w1[4], w1[5])
            ROWFMA(a1x, a1y, a1z, a1w, t2a, t2b, w1[6], w1[7], w1[8])
            ROWFMA(a2x, a2y, a2z, a2w, t0a, t0b, w2[0], w2[1], w2[2])
            ROWFMA(a2x, a2y, a2z, a2w, t1a, t1b, w2[3], w2[4], w2[5])
            ROWFMA(a2x, a2y, a2z, a2w, t2a, t2b, w2[6], w2[7], w2[8])
            ROWFMA(a3x, a3y, a3z, a3w, t0a, t0b, w3[0], w3[1], w3[2])
            ROWFMA(a3x, a3y, a3z, a3w, t1a, t1b, w3[3], w3[4], w3[5])
            ROWFMA(a3x, a3y, a3z, a3w, t2a, t2b, w3[6], w3[7], w3[8])
        }
        if (pv) {
            float* pb = wsf + PART_OFF + ((size_t)z * SIZE_LIMIT + slot0) * NPIX + 4 * (size_t)i4;
            *(float4*)pb = make_float4(a0x, a0y, a0z, a0w);
            if (v1) *(float4*)(pb + NPIX)     = make_float4(a1x, a1y, a1z, a1w);
            if (v2) *(float4*)(pb + 2 * NPIX) = make_float4(a2x, a2y, a2z, a2w);
            if (v3) *(float4*)(pb + 3 * NPIX) = make_float4(a3x, a3y, a3z, a3w);
        }
    }
}

// ---- 4. combine 16 slabs + BN (batch stats) + ReLU, 1024 threads ----
__global__ __launch_bounds__(1024) void k_fin(const int* __restrict__ wsi,
                                              const float* __restrict__ wsf,
                                              const float* __restrict__ gamma,
                                              const float* __restrict__ beta,
                                              float* __restrict__ y) {
    int s = blockIdx.x, tid = threadIdx.x;
    if (s >= wsi[NACT_OFF]) return;
    int o = wsi[COMPACT_OFF + s];
    const float* base0 = wsf + PART_OFF + (size_t)s * NPIX;
    float4 v = make_float4(0.f, 0.f, 0.f, 0.f);
    if (tid < NPIX4) {
        const float* bp = base0 + 4 * (size_t)tid;
        #pragma unroll
        for (int zz = 0; zz < KSPLIT; zz++) {
            float4 t = *(const float4*)(bp + (size_t)zz * SIZE_LIMIT * NPIX);
            v.x += t.x; v.y += t.y; v.z += t.z; v.w += t.w;
        }
    }
    float sum = v.x + v.y + v.z + v.w;
    float sq = v.x * v.x + v.y * v.y + v.z * v.z + v.w * v.w;
    __shared__ float rs[1024], rq[1024];
    __shared__ float mv[2];
    rs[tid] = sum; rq[tid] = sq;
    __syncthreads();
    for (int off = 512; off > 0; off >>= 1) {
        if (tid < off) { rs[tid] += rs[tid + off]; rq[tid] += rq[tid + off]; }
        __syncthreads();
    }
    if (tid == 0) {
        float mean = rs[0] / (float)NPIX;
        float var = rq[0] / (float)NPIX - mean * mean;
        float inv = 1.0f / sqrtf(var + EPS);
        float sc = inv * gamma[o];
        mv[0] = sc;
        mv[1] = beta[o] - mean * sc;
    }
    __syncthreads();
    if (tid < NPIX4) {
        float scale = mv[0], shift = mv[1];
        float4 a = v;
        a.x = fmaf(a.x, scale, shift); a.x = (a.x > 0.f) ? a.x : 0.f;
        a.y = fmaf(a.y, scale, shift); a.y = (a.y > 0.f) ? a.y : 0.f;
        a.z = fmaf(a.z, scale, shift); a.z = (a.z > 0.f) ? a.z : 0.f;
        a.w = fmaf(a.w, scale, shift); a.w = (a.w > 0.f) ? a.w : 0.f;
        ((float4*)(y + (size_t)o * NPIX))[tid] = a;
    }
}

extern "C" void kernel_launch(void* const* d_in, const int* in_sizes, int n_in,
                              void* d_out, int out_size, void* d_ws, size_t ws_size,
                              hipStream_t stream) {
    const float* x       = (const float*)d_in[0];
    const float* whole_w = (const float*)d_in[1];
    const float* rm_w    = (const float*)d_in[2];
    const float* rm_q    = (const float*)d_in[3];
    const float* gamma   = (const float*)d_in[4];
    const float* beta    = (const float*)d_in[5];
    float* out = (float*)d_out;
    float* wsf = (float*)d_ws;
    int*   wsi = (int*)d_ws;

    k_stage1<<<S1BLOCKS, 256, 0, stream>>>(x, whole_w, rm_w, wsf, wsi, out);
    k_select<<<1, OUT_CH, 0, stream>>>(rm_q, wsf, wsi);
    k_conv<<<dim3(PT4, SPGRID, KSPLIT), 256, 0, stream>>>(whole_w, wsi, wsf);
    k_fin<<<SIZE_LIMIT, 1024, 0, stream>>>(wsi, wsf, gamma, beta, out);
}

// Round 16
// 56.707 us; speedup vs baseline: 1.4599x; 1.0722x over previous
//
#include <hip/hip_runtime.h>

#define IN_CH 256
#define OUT_CH 512
#define HW 56
#define NPIX (HW * HW)            // 3136
#define NPIX4 (NPIX / 4)          // 784
#define WROW (IN_CH * 9)          // 2304
#define NT 10
#define HB 8
#define NDOT (NT * HB)            // 80
#define SIZE_LIMIT 256
#define EPS 1e-3f

// stage1 roles: wsig (4-ch x 2-table blocks) + query + zero-y + pad-x
#define WOTILE 4
#define TPB 2                                   // tables per block
#define TGROUPS (NT / TPB)                      // 5
#define WSBLOCKS ((OUT_CH / WOTILE) * TGROUPS)  // 640
#define QBLOCKS IN_CH                           // 256
#define ZBLOCKS OUT_CH                          // 512
#define PBLOCKS IN_CH                           // 256
#define S1BLOCKS (WSBLOCKS + QBLOCKS + ZBLOCKS + PBLOCKS)  // 1664

// conv tiling: 4 px/thread (float4), 4 out-ch, 16 in-ch, slot-quad loop
#define COTILE 4
#define SPGRID 8
#define PT4 4                                   // ceil(784/256)
#define KSPLIT 16
#define KCH (IN_CH / KSPLIT)                    // 16

// padded x: [58 rows][64 cols] per channel
#define XPW 64
#define XPSZ (58 * XPW)                         // 3712 floats

// ws offsets (4-byte units)
#define Q_OFF       0
#define QADDR_OFF   256
#define WADDR_OFF   288
#define SLOT_OFF    (WADDR_OFF + NT * OUT_CH)
#define NACT_OFF    (SLOT_OFF + OUT_CH)
#define COMPACT_OFF (NACT_OFF + 32)
#define PART_OFF    16384                       // 16*256*3136 f ≈ 51.4 MB
#define XPAD_OFF    (PART_OFF + KSPLIT * SIZE_LIMIT * NPIX)  // + 3.8 MB

// NOTE: parameter names must not collide with float4 member names (.x/.y/.z/.w)
#define DOT4(A_, B_) ((A_).x * (B_).x + (A_).y * (B_).y + (A_).z * (B_).z + (A_).w * (B_).w)

#define ROWFMA(ax, ay, az, aw, A_, B_, k0, k1, k2)                 \
    ax = fmaf((A_).x, k0, fmaf((A_).y, k1, fmaf((A_).z, k2, ax))); \
    ay = fmaf((A_).y, k0, fmaf((A_).z, k1, fmaf((A_).w, k2, ay))); \
    az = fmaf((A_).z, k0, fmaf((A_).w, k1, fmaf((B_).x, k2, az))); \
    aw = fmaf((A_).w, k0, fmaf((B_).x, k1, fmaf((B_).y, k2, aw)));

#define RED64(a) for (int m = 32; m > 0; m >>= 1) a += __shfl_xor(a, m, 64);

// ---- 1. fused: weight signatures + query avg-pool + zero y + pad x ----
__global__ __launch_bounds__(256) void k_stage1(const float* __restrict__ x,
                                                const float* __restrict__ whole_w,
                                                const float* __restrict__ rm_w,
                                                float* __restrict__ wsf,
                                                int* __restrict__ wsi,
                                                float* __restrict__ y) {
    __shared__ float4 sW4[WOTILE][WROW / 4];   // 36.9 KB
    __shared__ int bits[TPB * HB][WOTILE];
    __shared__ float red[256];
    int bid = blockIdx.x, tid = threadIdx.x;

    if (bid < WSBLOCKS) {
        // wsig role: 4 channels x 2 tables; 4 waves x 4 dots x 4 ch register tile
        int ogrp = bid / TGROUPS, tp = bid - ogrp * TGROUPS;
        int o0 = ogrp * WOTILE;
        const float4* w4 = (const float4*)(whole_w + (size_t)o0 * WROW);
        for (int i = tid; i < WOTILE * (WROW / 4); i += 256)
            sW4[i / (WROW / 4)][i % (WROW / 4)] = w4[i];
        __syncthreads();
        int wid = tid >> 6, lane = tid & 63;
        int d0 = tp * (TPB * HB) + wid * 4;   // 4 waves x 4 dots = 16 dots (2 tables)
        const float4* r0 = (const float4*)(rm_w + (size_t)d0 * WROW);
        const float4* r1 = (const float4*)(rm_w + (size_t)(d0 + 1) * WROW);
        const float4* r2 = (const float4*)(rm_w + (size_t)(d0 + 2) * WROW);
        const float4* r3 = (const float4*)(rm_w + (size_t)(d0 + 3) * WROW);
        float a00 = 0.f, a01 = 0.f, a02 = 0.f, a03 = 0.f;
        float a10 = 0.f, a11 = 0.f, a12 = 0.f, a13 = 0.f;
        float a20 = 0.f, a21 = 0.f, a22 = 0.f, a23 = 0.f;
        float a30 = 0.f, a31 = 0.f, a32 = 0.f, a33 = 0.f;
        for (int i = lane; i < WROW / 4; i += 64) {  // 9 iters
            float4 v0 = r0[i], v1 = r1[i], v2 = r2[i], v3 = r3[i];
            float4 u0 = sW4[0][i], u1 = sW4[1][i], u2 = sW4[2][i], u3 = sW4[3][i];
            a00 += DOT4(v0, u0); a01 += DOT4(v0, u1); a02 += DOT4(v0, u2); a03 += DOT4(v0, u3);
            a10 += DOT4(v1, u0); a11 += DOT4(v1, u1); a12 += DOT4(v1, u2); a13 += DOT4(v1, u3);
            a20 += DOT4(v2, u0); a21 += DOT4(v2, u1); a22 += DOT4(v2, u2); a23 += DOT4(v2, u3);
            a30 += DOT4(v3, u0); a31 += DOT4(v3, u1); a32 += DOT4(v3, u2); a33 += DOT4(v3, u3);
        }
        RED64(a00) RED64(a01) RED64(a02) RED64(a03)
        RED64(a10) RED64(a11) RED64(a12) RED64(a13)
        RED64(a20) RED64(a21) RED64(a22) RED64(a23)
        RED64(a30) RED64(a31) RED64(a32) RED64(a33)
        if (lane == 0) {
            int db = wid * 4;
            bits[db][0] = (a00 > 0.f); bits[db][1] = (a01 > 0.f);
            bits[db][2] = (a02 > 0.f); bits[db][3] = (a03 > 0.f);
            bits[db + 1][0] = (a10 > 0.f); bits[db + 1][1] = (a11 > 0.f);
            bits[db + 1][2] = (a12 > 0.f); bits[db + 1][3] = (a13 > 0.f);
            bits[db + 2][0] = (a20 > 0.f); bits[db + 2][1] = (a21 > 0.f);
            bits[db + 2][2] = (a22 > 0.f); bits[db + 2][3] = (a23 > 0.f);
            bits[db + 3][0] = (a30 > 0.f); bits[db + 3][1] = (a31 > 0.f);
            bits[db + 3][2] = (a32 > 0.f); bits[db + 3][3] = (a33 > 0.f);
        }
        __syncthreads();
        if (tid < TPB * WOTILE) {   // 8 packers: (table-local, channel)
            int tl = tid >> 2, j = tid & 3;
            int a = 0;
            #pragma unroll
            for (int h = 0; h < HB; h++) a |= bits[tl * HB + h][j] << (7 - h);
            wsi[WADDR_OFF + (tp * TPB + tl) * OUT_CH + o0 + j] = a;
        }
    } else if (bid < WSBLOCKS + QBLOCKS) {
        int c = bid - WSBLOCKS;
        const float* xc = x + (size_t)c * NPIX;
        float s = 0.f;
        for (int p = tid; p < NPIX; p += 256) s += xc[p];
        red[tid] = s;
        __syncthreads();
        for (int off = 128; off > 0; off >>= 1) {
            if (tid < off) red[tid] += red[tid + off];
            __syncthreads();
        }
        if (tid == 0) wsf[Q_OFF + c] = red[0] / (float)NPIX;
    } else if (bid < WSBLOCKS + QBLOCKS + ZBLOCKS) {
        int o = bid - WSBLOCKS - QBLOCKS;
        float4* y4 = (float4*)(y + (size_t)o * NPIX);
        float4 z4 = make_float4(0.f, 0.f, 0.f, 0.f);
        for (int i = tid; i < NPIX4; i += 256) y4[i] = z4;
    } else {
        int c = bid - WSBLOCKS - QBLOCKS - ZBLOCKS;
        const float* xc = x + (size_t)c * NPIX;
        float* xp = wsf + XPAD_OFF + (size_t)c * XPSZ;
        for (int i = tid; i < XPSZ; i += 256) {
            int rr = i >> 6, cc = i & 63;
            int sr = rr - 1, sc = cc - 1;
            float v = (sr >= 0 && sr < HW && sc >= 0 && sc < HW) ? xc[sr * HW + sc] : 0.f;
            xp[i] = v;
        }
    }
}

// ---- 2. fused: query signatures + histogram + top-k + compaction (512 thr) ----
__global__ void k_select(const float* __restrict__ rm_q, const float* __restrict__ wsf,
                         int* __restrict__ wsi) {
    int tid = threadIdx.x; // 512
    __shared__ float qs[IN_CH];
    __shared__ int qbits[NDOT];
    __shared__ int qsig[NT];
    __shared__ int hist[OUT_CH];
    __shared__ int sel[OUT_CH];
    if (tid < IN_CH) qs[tid] = wsf[Q_OFF + tid];
    __syncthreads();
    if (tid < NDOT * 4) {
        int d = tid >> 2, part = tid & 3;
        const float* r = rm_q + d * IN_CH + part * 64;
        const float* qq = qs + part * 64;
        float acc = 0.f;
        for (int k = 0; k < 64; k++) acc = fmaf(r[k], qq[k], acc);
        acc += __shfl_xor(acc, 1, 64);
        acc += __shfl_xor(acc, 2, 64);
        if (part == 0) qbits[d] = (acc > 0.f) ? 1 : 0;
    }
    __syncthreads();
    if (tid < NT) {
        int a = 0;
        #pragma unroll
        for (int h = 0; h < HB; h++) a |= qbits[tid * HB + h] << (7 - h);
        qsig[tid] = a;
        wsi[QADDR_OFF + tid] = a;
    }
    __syncthreads();
    int h = 0;
    for (int t = 0; t < NT; t++) h += (wsi[WADDR_OFF + t * OUT_CH + tid] == qsig[t]) ? 1 : 0;
    hist[tid] = h;
    __syncthreads();
    int rank = 0;
    for (int j = 0; j < OUT_CH; j++) {
        int hj = hist[j];
        rank += (hj > h || (hj == h && j < tid)) ? 1 : 0;
    }
    int s = (h > 0 && rank < SIZE_LIMIT) ? 1 : 0;
    sel[tid] = s;
    wsi[SLOT_OFF + tid] = 0;
    __syncthreads();
    if (s) {
        int pos = 0;
        for (int j = 0; j < tid; j++) pos += sel[j];
        wsi[COMPACT_OFF + pos] = tid;
        wsi[SLOT_OFF + tid] = pos + 1;
    }
    if (tid == 0) {
        int c = 0;
        for (int j = 0; j < OUT_CH; j++) c += sel[j];
        wsi[NACT_OFF] = c;
    }
}

// ---- 3. sparse conv on padded x: 4 out-ch, named scalars only ----
__global__ __launch_bounds__(256) void k_conv(const float* __restrict__ whole_w,
                                              const int* __restrict__ wsi,
                                              float* __restrict__ wsf) {
    int nact = wsi[NACT_OFF];
    int tid = threadIdx.x;
    int z = blockIdx.z;
    int i4 = blockIdx.x * 256 + tid;
    bool pv = i4 < NPIX4;
    int i4c = pv ? i4 : 0;
    int r = i4c / 14, g4 = i4c - r * 14;
    const float* xpb = wsf + XPAD_OFF + (size_t)z * KCH * XPSZ + r * XPW + 4 * g4;

    for (int sp = blockIdx.y; sp * COTILE < nact; sp += SPGRID) {
        int slot0 = sp * COTILE;
        bool v1 = (slot0 + 1) < nact, v2 = (slot0 + 2) < nact, v3 = (slot0 + 3) < nact;
        int o0 = wsi[COMPACT_OFF + slot0];
        int o1 = v1 ? wsi[COMPACT_OFF + slot0 + 1] : o0;
        int o2 = v2 ? wsi[COMPACT_OFF + slot0 + 2] : o0;
        int o3 = v3 ? wsi[COMPACT_OFF + slot0 + 3] : o0;
        const float* wp0 = whole_w + (size_t)__builtin_amdgcn_readfirstlane(o0) * WROW + z * (KCH * 9);
        const float* wp1 = whole_w + (size_t)__builtin_amdgcn_readfirstlane(o1) * WROW + z * (KCH * 9);
        const float* wp2 = whole_w + (size_t)__builtin_amdgcn_readfirstlane(o2) * WROW + z * (KCH * 9);
        const float* wp3 = whole_w + (size_t)__builtin_amdgcn_readfirstlane(o3) * WROW + z * (KCH * 9);

        float a0x = 0.f, a0y = 0.f, a0z = 0.f, a0w = 0.f;
        float a1x = 0.f, a1y = 0.f, a1z = 0.f, a1w = 0.f;
        float a2x = 0.f, a2y = 0.f, a2z = 0.f, a2w = 0.f;
        float a3x = 0.f, a3y = 0.f, a3z = 0.f, a3w = 0.f;
        for (int c = 0; c < KCH; ++c) {
            const float* xc = xpb + (size_t)c * XPSZ;
            float4 t0a = *(const float4*)(xc);
            float4 t0b = *(const float4*)(xc + 4);
            float4 t1a = *(const float4*)(xc + XPW);
            float4 t1b = *(const float4*)(xc + XPW + 4);
            float4 t2a = *(const float4*)(xc + 2 * XPW);
            float4 t2b = *(const float4*)(xc + 2 * XPW + 4);
            const float* w0 = wp0 + c * 9;
            const float* w1 = wp1 + c * 9;
            const float* w2 = wp2 + c * 9;
            const float* w3 = wp3 + c * 9;
            ROWFMA(a0x, a0y, a0z, a0w, t0a, t0b, w0[0], w0[1], w0[2])
            ROWFMA(a0x, a0y, a0z, a0w, t1a, t1b, w0[3], w0[4], w0[5])
            ROWFMA(a0x, a0y, a0z, a0w, t2a, t2b, w0[6], w0[7], w0[8])
            ROWFMA(a1x, a1y, a1z, a1w, t0a, t0b, w1[0], w1[1], w1[2])
            ROWFMA(a1x, a1y, a1z, a1w, t1a, t1b, w1[3], w1[4], w1[5])
            ROWFMA(a1x, a1y, a1z, a1w, t2a, t2b, w1[6], w1[7], w1[8])
            ROWFMA(a2x, a2y, a2z, a2w, t0a, t0b, w2[0], w2[1], w2[2])
            ROWFMA(a2x, a2y, a2z, a2w, t1a, t1b, w2[3], w2[4], w2[5])
            ROWFMA(a2x, a2y, a2z, a2w, t2a, t2b, w2[6], w2[7], w2[8])
            ROWFMA(a3x, a3y, a3z, a3w, t0a, t0b, w3[0], w3[1], w3[2])
            ROWFMA(a3x, a3y, a3z, a3w, t1a, t1b, w3[3], w3[4], w3[5])
            ROWFMA(a3x, a3y, a3z, a3w, t2a, t2b, w3[6], w3[7], w3[8])
        }
        if (pv) {
            float* pb = wsf + PART_OFF + ((size_t)z * SIZE_LIMIT + slot0) * NPIX + 4 * (size_t)i4;
            *(float4*)pb = make_float4(a0x, a0y, a0z, a0w);
            if (v1) *(float4*)(pb + NPIX)     = make_float4(a1x, a1y, a1z, a1w);
            if (v2) *(float4*)(pb + 2 * NPIX) = make_float4(a2x, a2y, a2z, a2w);
            if (v3) *(float4*)(pb + 3 * NPIX) = make_float4(a3x, a3y, a3z, a3w);
        }
    }
}

// ---- 4. combine 16 slabs + BN (batch stats) + ReLU, 1024 threads ----
__global__ __launch_bounds__(1024) void k_fin(const int* __restrict__ wsi,
                                              const float* __restrict__ wsf,
                                              const float* __restrict__ gamma,
                                              const float* __restrict__ beta,
                                              float* __restrict__ y) {
    int s = blockIdx.x, tid = threadIdx.x;
    if (s >= wsi[NACT_OFF]) return;
    int o = wsi[COMPACT_OFF + s];
    const float* base0 = wsf + PART_OFF + (size_t)s * NPIX;
    float4 v = make_float4(0.f, 0.f, 0.f, 0.f);
    if (tid < NPIX4) {
        const float* bp = base0 + 4 * (size_t)tid;
        #pragma unroll
        for (int zz = 0; zz < KSPLIT; zz++) {
            float4 t = *(const float4*)(bp + (size_t)zz * SIZE_LIMIT * NPIX);
            v.x += t.x; v.y += t.y; v.z += t.z; v.w += t.w;
        }
    }
    float sum = v.x + v.y + v.z + v.w;
    float sq = v.x * v.x + v.y * v.y + v.z * v.z + v.w * v.w;
    __shared__ float rs[1024], rq[1024];
    __shared__ float mv[2];
    rs[tid] = sum; rq[tid] = sq;
    __syncthreads();
    for (int off = 512; off > 0; off >>= 1) {
        if (tid < off) { rs[tid] += rs[tid + off]; rq[tid] += rq[tid + off]; }
        __syncthreads();
    }
    if (tid == 0) {
        float mean = rs[0] / (float)NPIX;
        float var = rq[0] / (float)NPIX - mean * mean;
        float inv = 1.0f / sqrtf(var + EPS);
        float sc = inv * gamma[o];
        mv[0] = sc;
        mv[1] = beta[o] - mean * sc;
    }
    __syncthreads();
    if (tid < NPIX4) {
        float scale = mv[0], shift = mv[1];
        float4 a = v;
        a.x = fmaf(a.x, scale, shift); a.x = (a.x > 0.f) ? a.x : 0.f;
        a.y = fmaf(a.y, scale, shift); a.y = (a.y > 0.f) ? a.y : 0.f;
        a.z = fmaf(a.z, scale, shift); a.z = (a.z > 0.f) ? a.z : 0.f;
        a.w = fmaf(a.w, scale, shift); a.w = (a.w > 0.f) ? a.w : 0.f;
        ((float4*)(y + (size_t)o * NPIX))[tid] = a;
    }
}

extern "C" void kernel_launch(void* const* d_in, const int* in_sizes, int n_in,
                              void* d_out, int out_size, void* d_ws, size_t ws_size,
                              hipStream_t stream) {
    const float* x       = (const float*)d_in[0];
    const float* whole_w = (const float*)d_in[1];
    const float* rm_w    = (const float*)d_in[2];
    const float* rm_q    = (const float*)d_in[3];
    const float* gamma   = (const float*)d_in[4];
    const float* beta    = (const float*)d_in[5];
    float* out = (float*)d_out;
    float* wsf = (float*)d_ws;
    int*   wsi = (int*)d_ws;

    k_stage1<<<S1BLOCKS, 256, 0, stream>>>(x, whole_w, rm_w, wsf, wsi, out);
    k_select<<<1, OUT_CH, 0, stream>>>(rm_q, wsf, wsi);
    k_conv<<<dim3(PT4, SPGRID, KSPLIT), 256, 0, stream>>>(whole_w, wsi, wsf);
    k_fin<<<SIZE_LIMIT, 1024, 0, stream>>>(wsi, wsf, gamma, beta, out);
}